// Round 1
// baseline (452.778 us; speedup 1.0000x reference)
//
#include <hip/hip_runtime.h>
#include <hip/hip_bf16.h>

// Problem constants (B,T,E,H,D) = (4,1024,1024,16,64)
#define BB 4
#define TT 1024
#define EE 1024
#define HH 16
#define DD 64
#define MM 4096    // B*T rows
#define NQKV 3072  // q|k|v packed cols
#define E4 4096    // 4*E

using short8  = __attribute__((ext_vector_type(8))) short;
using short4v = __attribute__((ext_vector_type(4))) short;
using f32x4   = __attribute__((ext_vector_type(4))) float;

__device__ __forceinline__ short f2bf(float f) {
    __hip_bfloat16 h = __float2bfloat16(f);
    return *reinterpret_cast<short*>(&h);
}

// ---------------- weight conversion ----------------
__global__ __launch_bounds__(256) void cvt_kernel(const float* __restrict__ in,
                                                  short* __restrict__ out, int n) {
    int i = blockIdx.x * 256 + threadIdx.x;
    if (i < n) out[i] = f2bf(in[i]);
}

// pack Wq/Wk/Wv (H,E,D) -> bf16 [E][3072], col = which*1024 + head*64 + d
__global__ __launch_bounds__(256) void pack_qkv_kernel(const float* __restrict__ Wq,
                                                       const float* __restrict__ Wk,
                                                       const float* __restrict__ Wv,
                                                       short* __restrict__ out) {
    int i = blockIdx.x * 256 + threadIdx.x;       // < EE*NQKV
    int e = i / NQKV;
    int c = i - e * NQKV;
    int which = c >> 10;
    int hd = c & 1023;
    int head = hd >> 6;
    int d = hd & 63;
    const float* src = (which == 0) ? Wq : (which == 1) ? Wk : Wv;
    out[i] = f2bf(src[((size_t)head * EE + e) * DD + d]);
}

// ---------------- LayerNorm (fp32 in -> bf16 out) ----------------
__global__ __launch_bounds__(256) void ln_kernel(const float* __restrict__ x,
                                                 const float* __restrict__ g,
                                                 const float* __restrict__ b,
                                                 short* __restrict__ out) {
    __shared__ float red[4];
    const int row = blockIdx.x;
    const int tid = threadIdx.x;
    float4 v = *(const float4*)&x[(size_t)row * EE + tid * 4];
    float s = v.x + v.y + v.z + v.w;
#pragma unroll
    for (int off = 32; off >= 1; off >>= 1) s += __shfl_xor(s, off, 64);
    if ((tid & 63) == 0) red[tid >> 6] = s;
    __syncthreads();
    float mean = (red[0] + red[1] + red[2] + red[3]) * (1.0f / EE);
    __syncthreads();
    float d0 = v.x - mean, d1 = v.y - mean, d2 = v.z - mean, d3 = v.w - mean;
    s = d0 * d0 + d1 * d1 + d2 * d2 + d3 * d3;
#pragma unroll
    for (int off = 32; off >= 1; off >>= 1) s += __shfl_xor(s, off, 64);
    if ((tid & 63) == 0) red[tid >> 6] = s;
    __syncthreads();
    float var = (red[0] + red[1] + red[2] + red[3]) * (1.0f / EE);
    float rstd = rsqrtf(var + 1e-5f);
    int c = tid * 4;
    short4v o;
    o[0] = f2bf(d0 * rstd * g[c + 0] + b[c + 0]);
    o[1] = f2bf(d1 * rstd * g[c + 1] + b[c + 1]);
    o[2] = f2bf(d2 * rstd * g[c + 2] + b[c + 2]);
    o[3] = f2bf(d3 * rstd * g[c + 3] + b[c + 3]);
    *(short4v*)&out[(size_t)row * EE + c] = o;
}

// ---------------- bf16 GEMM: C[M,N] = A[M,K] @ B[K,N] (+bias)(ReLU)(+resid) ----------------
// 64x64 tile, BK=64, 4 waves (2x2), mfma 16x16x32. B staged transposed in LDS
// so both operand fragment reads are contiguous ds_read_b128. +8 stride pad.
template <bool HAS_BIAS, bool RELU, bool RESID, bool OUT_BF16>
__global__ __launch_bounds__(256) void gemm_kernel(const short* __restrict__ A,
                                                   const short* __restrict__ Bm,
                                                   const float* __restrict__ bias,
                                                   const float* __restrict__ resid,
                                                   void* __restrict__ outp,
                                                   int M, int N, int K) {
    __shared__ short As[64][72];
    __shared__ short BsT[64][72];
    const int tid = threadIdx.x;
    const int lane = tid & 63;
    const int wid = tid >> 6;
    const int wr = wid >> 1, wc = wid & 1;
    const int l15 = lane & 15, lhi = lane >> 4;
    const int row0 = blockIdx.y * 64, col0 = blockIdx.x * 64;

    const int ar = tid >> 2, ac = (tid & 3) * 16;   // A: 64 rows x 64 k
    const int bk = tid >> 2, bn0 = (tid & 3) * 16;  // B: 64 k x 64 n

    f32x4 acc[2][2] = {};

    for (int k0 = 0; k0 < K; k0 += 64) {
        short8 a0 = *(const short8*)&A[(size_t)(row0 + ar) * K + k0 + ac];
        short8 a1 = *(const short8*)&A[(size_t)(row0 + ar) * K + k0 + ac + 8];
        short8 b0 = *(const short8*)&Bm[(size_t)(k0 + bk) * N + col0 + bn0];
        short8 b1 = *(const short8*)&Bm[(size_t)(k0 + bk) * N + col0 + bn0 + 8];
        __syncthreads();  // previous iter's fragment reads done before overwrite
        *(short8*)&As[ar][ac] = a0;
        *(short8*)&As[ar][ac + 8] = a1;
#pragma unroll
        for (int j = 0; j < 8; ++j) BsT[bn0 + j][bk] = b0[j];
#pragma unroll
        for (int j = 0; j < 8; ++j) BsT[bn0 + 8 + j][bk] = b1[j];
        __syncthreads();
#pragma unroll
        for (int ks = 0; ks < 2; ++ks) {
            short8 af[2], bf[2];
            af[0] = *(const short8*)&As[wr * 32 + l15][ks * 32 + lhi * 8];
            af[1] = *(const short8*)&As[wr * 32 + 16 + l15][ks * 32 + lhi * 8];
            bf[0] = *(const short8*)&BsT[wc * 32 + l15][ks * 32 + lhi * 8];
            bf[1] = *(const short8*)&BsT[wc * 32 + 16 + l15][ks * 32 + lhi * 8];
#pragma unroll
            for (int mi = 0; mi < 2; ++mi)
#pragma unroll
                for (int nt = 0; nt < 2; ++nt)
                    acc[mi][nt] = __builtin_amdgcn_mfma_f32_16x16x32_bf16(
                        af[mi], bf[nt], acc[mi][nt], 0, 0, 0);
        }
    }

    float* outf = (float*)outp;
    short* outb = (short*)outp;
#pragma unroll
    for (int mi = 0; mi < 2; ++mi)
#pragma unroll
        for (int nt = 0; nt < 2; ++nt)
#pragma unroll
            for (int r = 0; r < 4; ++r) {
                int row = row0 + wr * 32 + mi * 16 + lhi * 4 + r;
                int col = col0 + wc * 32 + nt * 16 + l15;
                float v = acc[mi][nt][r];
                if (HAS_BIAS) v += bias[col];
                if (RELU) v = fmaxf(v, 0.f);
                if (RESID) v += resid[(size_t)row * N + col];
                if (OUT_BF16) outb[(size_t)row * N + col] = f2bf(v);
                else outf[(size_t)row * N + col] = v;
            }
}

// ---------------- flash attention ----------------
// 1 wave per (b, h, 16 q-rows). qkv bf16 [4096][3072]: q at col h*64, k at
// 1024+h*64, v at 2048+h*64. Online softmax, no scale, non-causal.
__global__ __launch_bounds__(64) void attn_kernel(const short* __restrict__ qkv,
                                                  short* __restrict__ obuf) {
    __shared__ short Pl[16][40];
    const int lane = threadIdx.x;
    const int l15 = lane & 15, lhi = lane >> 4;
    const int bid = blockIdx.x;
    const int b = bid >> 10;          // /(H * T/16)
    const int rem = bid & 1023;
    const int h = rem >> 6;
    const int q0 = (rem & 63) << 4;
    const size_t rbase = (size_t)b * TT;
    const int hq = h * 64;

    short8 aq[2];
#pragma unroll
    for (int ks = 0; ks < 2; ++ks)
        aq[ks] = *(const short8*)&qkv[(rbase + q0 + l15) * NQKV + hq + ks * 32 + lhi * 8];

    float mrun[4], lsum[4];
    f32x4 o[4] = {};
#pragma unroll
    for (int r = 0; r < 4; ++r) { mrun[r] = -INFINITY; lsum[r] = 0.f; }

    for (int st = 0; st < TT; st += 32) {
        f32x4 s[2] = {};
#pragma unroll
        for (int nt = 0; nt < 2; ++nt)
#pragma unroll
            for (int ks = 0; ks < 2; ++ks) {
                short8 kf = *(const short8*)&qkv[(rbase + st + nt * 16 + l15) * NQKV +
                                                 1024 + hq + ks * 32 + lhi * 8];
                s[nt] = __builtin_amdgcn_mfma_f32_16x16x32_bf16(aq[ks], kf, s[nt], 0, 0, 0);
            }
        float fac[4], p[2][4];
#pragma unroll
        for (int r = 0; r < 4; ++r) {
            float tmax = fmaxf(s[0][r], s[1][r]);
#pragma unroll
            for (int off = 1; off < 16; off <<= 1)
                tmax = fmaxf(tmax, __shfl_xor(tmax, off, 16));
            float mnew = fmaxf(mrun[r], tmax);
            fac[r] = __expf(mrun[r] - mnew);
            p[0][r] = __expf(s[0][r] - mnew);
            p[1][r] = __expf(s[1][r] - mnew);
            float rs = p[0][r] + p[1][r];
#pragma unroll
            for (int off = 1; off < 16; off <<= 1) rs += __shfl_xor(rs, off, 16);
            lsum[r] = lsum[r] * fac[r] + rs;
            mrun[r] = mnew;
        }
#pragma unroll
        for (int dt = 0; dt < 4; ++dt)
#pragma unroll
            for (int r = 0; r < 4; ++r) o[dt][r] *= fac[r];

        __syncthreads();
#pragma unroll
        for (int nt = 0; nt < 2; ++nt)
#pragma unroll
            for (int r = 0; r < 4; ++r)
                Pl[lhi * 4 + r][nt * 16 + l15] = f2bf(p[nt][r]);
        __syncthreads();
        short8 pa = *(const short8*)&Pl[l15][lhi * 8];
#pragma unroll
        for (int dt = 0; dt < 4; ++dt) {
            short8 vf;
#pragma unroll
            for (int j = 0; j < 8; ++j)
                vf[j] = qkv[(rbase + st + lhi * 8 + j) * NQKV + 2048 + hq + dt * 16 + l15];
            o[dt] = __builtin_amdgcn_mfma_f32_16x16x32_bf16(pa, vf, o[dt], 0, 0, 0);
        }
    }
#pragma unroll
    for (int r = 0; r < 4; ++r) lsum[r] = 1.0f / lsum[r];
#pragma unroll
    for (int dt = 0; dt < 4; ++dt)
#pragma unroll
        for (int r = 0; r < 4; ++r)
            obuf[(rbase + q0 + lhi * 4 + r) * EE + hq + dt * 16 + l15] =
                f2bf(o[dt][r] * lsum[r]);
}

// ---------------- launch ----------------
extern "C" void kernel_launch(void* const* d_in, const int* in_sizes, int n_in,
                              void* d_out, int out_size, void* d_ws, size_t ws_size,
                              hipStream_t stream) {
    const float* x   = (const float*)d_in[0];
    const float* g1  = (const float*)d_in[1];
    const float* be1 = (const float*)d_in[2];
    const float* Wq  = (const float*)d_in[3];
    const float* Wk  = (const float*)d_in[4];
    const float* Wv  = (const float*)d_in[5];
    const float* Wp  = (const float*)d_in[6];
    const float* bp  = (const float*)d_in[7];
    const float* g2  = (const float*)d_in[8];
    const float* be2 = (const float*)d_in[9];
    const float* W1  = (const float*)d_in[10];
    const float* b1f = (const float*)d_in[11];
    const float* W2  = (const float*)d_in[12];
    const float* b2f = (const float*)d_in[13];

    char* p = (char*)d_ws;
    short* h_bf   = (short*)p; p += (size_t)MM * EE * 2;
    short* wqkv   = (short*)p; p += (size_t)EE * NQKV * 2;
    short* qkv    = (short*)p; p += (size_t)MM * NQKV * 2;
    short* o_bf   = (short*)p; p += (size_t)MM * EE * 2;
    short* wp_bf  = (short*)p; p += (size_t)EE * EE * 2;
    float* x1     = (float*)p; p += (size_t)MM * EE * 4;
    short* h2_bf  = (short*)p; p += (size_t)MM * EE * 2;
    short* w1_bf  = (short*)p; p += (size_t)EE * E4 * 2;
    short* mid_bf = (short*)p; p += (size_t)MM * E4 * 2;
    short* w2_bf  = (short*)p; p += (size_t)E4 * EE * 2;

    pack_qkv_kernel<<<(EE * NQKV) / 256, 256, 0, stream>>>(Wq, Wk, Wv, wqkv);
    cvt_kernel<<<(EE * EE) / 256, 256, 0, stream>>>(Wp, wp_bf, EE * EE);
    cvt_kernel<<<(EE * E4) / 256, 256, 0, stream>>>(W1, w1_bf, EE * E4);
    cvt_kernel<<<(E4 * EE) / 256, 256, 0, stream>>>(W2, w2_bf, E4 * EE);

    ln_kernel<<<MM, 256, 0, stream>>>(x, g1, be1, h_bf);

    gemm_kernel<false, false, false, true>
        <<<dim3(NQKV / 64, MM / 64), 256, 0, stream>>>(h_bf, wqkv, nullptr, nullptr,
                                                       qkv, MM, NQKV, EE);

    attn_kernel<<<BB * HH * (TT / 16), 64, 0, stream>>>(qkv, o_bf);

    gemm_kernel<true, false, true, false>
        <<<dim3(EE / 64, MM / 64), 256, 0, stream>>>(o_bf, wp_bf, bp, x, x1, MM, EE, EE);

    ln_kernel<<<MM, 256, 0, stream>>>(x1, g2, be2, h2_bf);

    gemm_kernel<true, true, false, true>
        <<<dim3(E4 / 64, MM / 64), 256, 0, stream>>>(h2_bf, w1_bf, b1f, nullptr,
                                                     mid_bf, MM, E4, EE);

    gemm_kernel<true, false, true, false>
        <<<dim3(EE / 64, MM / 64), 256, 0, stream>>>(mid_bf, w2_bf, b2f, x1,
                                                     (float*)d_out, MM, EE, E4);
}

// Round 2
// 328.057 us; speedup vs baseline: 1.3802x; 1.3802x over previous
//
#include <hip/hip_runtime.h>
#include <hip/hip_bf16.h>

// Problem constants (B,T,E,H,D) = (4,1024,1024,16,64)
#define BB 4
#define TT 1024
#define EE 1024
#define HH 16
#define DD 64
#define MM 4096    // B*T rows
#define NQKV 3072  // q|k|v packed cols
#define E4 4096    // 4*E

using short8  = __attribute__((ext_vector_type(8))) short;
using short4v = __attribute__((ext_vector_type(4))) short;
using f32x4   = __attribute__((ext_vector_type(4))) float;

__device__ __forceinline__ short f2bf(float f) {
    __hip_bfloat16 h = __float2bfloat16(f);
    return *reinterpret_cast<short*>(&h);
}

// async global->LDS, 16B per lane. LDS dest is wave-uniform base + lane*16.
__device__ __forceinline__ void gld16(const void* g, void* l) {
    __builtin_amdgcn_global_load_lds((__attribute__((address_space(1))) void*)g,
                                     (__attribute__((address_space(3))) void*)l,
                                     16, 0, 0);
}

// ---------------- transpose + convert: in fp32 [R][C] -> out bf16 [C][R] ----------------
__global__ __launch_bounds__(256) void tcvt_kernel(const float* __restrict__ in,
                                                   short* __restrict__ out,
                                                   int R, int C) {
    __shared__ short tile[64][65];
    const int c0 = blockIdx.x * 64, r0 = blockIdx.y * 64;
    const int tr = threadIdx.x >> 6;   // 0..3
    const int tc = threadIdx.x & 63;
#pragma unroll
    for (int i = 0; i < 16; ++i) {
        int r = i * 4 + tr;
        tile[tc][r] = f2bf(in[(size_t)(r0 + r) * C + c0 + tc]);
    }
    __syncthreads();
#pragma unroll
    for (int i = 0; i < 16; ++i) {
        int c = i * 4 + tr;
        out[(size_t)(c0 + c) * R + r0 + tc] = tile[c][tc];
    }
}

// pack Wq/Wk/Wv (H,E,D) -> bf16 W^T layout [3072][1024]: row = which*1024+head*64+d, col = e
__global__ __launch_bounds__(256) void pack_qkv_t(const float* __restrict__ Wq,
                                                  const float* __restrict__ Wk,
                                                  const float* __restrict__ Wv,
                                                  short* __restrict__ out) {
    __shared__ short tile[64][65];
    const int m = blockIdx.y;            // 0..47
    const int which = m >> 4, head = m & 15;
    const float* src = ((which == 0) ? Wq : (which == 1) ? Wk : Wv) + (size_t)head * EE * DD;
    const int e0 = blockIdx.x * 64;
    const int tr = threadIdx.x >> 6, tc = threadIdx.x & 63;
#pragma unroll
    for (int i = 0; i < 16; ++i) {
        int e = i * 4 + tr;
        tile[tc][e] = f2bf(src[(size_t)(e0 + e) * DD + tc]);   // tile[d][e_local]
    }
    __syncthreads();
#pragma unroll
    for (int i = 0; i < 16; ++i) {
        int d = i * 4 + tr;
        out[(size_t)(which * 1024 + head * 64 + d) * EE + e0 + tc] = tile[d][tc];
    }
}

// ---------------- LayerNorm (fp32 in -> bf16 out) ----------------
__global__ __launch_bounds__(256) void ln_kernel(const float* __restrict__ x,
                                                 const float* __restrict__ g,
                                                 const float* __restrict__ b,
                                                 short* __restrict__ out) {
    __shared__ float red[4];
    const int row = blockIdx.x;
    const int tid = threadIdx.x;
    float4 v = *(const float4*)&x[(size_t)row * EE + tid * 4];
    float s = v.x + v.y + v.z + v.w;
#pragma unroll
    for (int off = 32; off >= 1; off >>= 1) s += __shfl_xor(s, off, 64);
    if ((tid & 63) == 0) red[tid >> 6] = s;
    __syncthreads();
    float mean = (red[0] + red[1] + red[2] + red[3]) * (1.0f / EE);
    __syncthreads();
    float d0 = v.x - mean, d1 = v.y - mean, d2 = v.z - mean, d3 = v.w - mean;
    s = d0 * d0 + d1 * d1 + d2 * d2 + d3 * d3;
#pragma unroll
    for (int off = 32; off >= 1; off >>= 1) s += __shfl_xor(s, off, 64);
    if ((tid & 63) == 0) red[tid >> 6] = s;
    __syncthreads();
    float var = (red[0] + red[1] + red[2] + red[3]) * (1.0f / EE);
    float rstd = rsqrtf(var + 1e-5f);
    int c = tid * 4;
    short4v o;
    o[0] = f2bf(d0 * rstd * g[c + 0] + b[c + 0]);
    o[1] = f2bf(d1 * rstd * g[c + 1] + b[c + 1]);
    o[2] = f2bf(d2 * rstd * g[c + 2] + b[c + 2]);
    o[3] = f2bf(d3 * rstd * g[c + 3] + b[c + 3]);
    *(short4v*)&out[(size_t)row * EE + c] = o;
}

// ---------------- bf16 GEMM (m97 structure): C[M,N] = A[M,K] @ B[K,N] ----------------
// Bt = B^T stored [N][K]. 128xBN tile, BK=64, 4 waves, global_load_lds(16) staging,
// linear LDS [rows][64] K-major, all fragment reads ds_read_b128.
template <int BN, bool HAS_BIAS, bool RELU, bool RESID, bool OUT_BF16>
__global__ __launch_bounds__(256) void gemm_bt(const short* __restrict__ A,
                                               const short* __restrict__ Bt,
                                               const float* __restrict__ bias,
                                               const float* __restrict__ resid,
                                               void* __restrict__ outp,
                                               int M, int N, int K) {
    constexpr int WRC = (BN == 128) ? 2 : 4;   // wave grid rows
    constexpr int WCC = (BN == 128) ? 2 : 1;   // wave grid cols
    constexpr int MI = 8 / WRC;                // 16-row frags per wave (4 or 2)
    constexpr int NI = BN / (16 * WCC);        // 16-col frags per wave (4)
    constexpr int BCH = BN / 32;               // B staging chunks

    __shared__ __align__(16) short As[128 * 64];
    __shared__ __align__(16) short Bs[BN * 64];

    const int tid = threadIdx.x;
    const int lane = tid & 63;
    const int wid = tid >> 6;
    const int wr = (WRC == 2) ? (wid >> 1) : wid;
    const int wc = (WCC == 2) ? (wid & 1) : 0;
    const int l15 = lane & 15, lhi = lane >> 4;
    const int row0 = blockIdx.y * 128, col0 = blockIdx.x * BN;

    const int srow = tid >> 3;           // 0..31 (row within 32-row staging chunk)
    const int scol = (tid & 7) * 8;      // k element within tile

    const int wrow0 = wr * (16 * MI);
    const int wcol0 = wc * (16 * NI);

    f32x4 acc[MI][NI] = {};

    for (int k0 = 0; k0 < K; k0 += 64) {
        __syncthreads();   // prev iter's fragment reads done before overwrite
#pragma unroll
        for (int ch = 0; ch < 4; ++ch)
            gld16(&A[(size_t)(row0 + ch * 32 + srow) * K + k0 + scol],
                  &As[ch * 2048 + wid * 512]);
#pragma unroll
        for (int ch = 0; ch < BCH; ++ch)
            gld16(&Bt[(size_t)(col0 + ch * 32 + srow) * K + k0 + scol],
                  &Bs[ch * 2048 + wid * 512]);
        __syncthreads();   // vmcnt(0) drain: tiles ready
#pragma unroll
        for (int ks = 0; ks < 2; ++ks) {
            short8 af[MI], bf[NI];
#pragma unroll
            for (int mi = 0; mi < MI; ++mi)
                af[mi] = *(const short8*)&As[(wrow0 + mi * 16 + l15) * 64 + ks * 32 + lhi * 8];
#pragma unroll
            for (int ni = 0; ni < NI; ++ni)
                bf[ni] = *(const short8*)&Bs[(wcol0 + ni * 16 + l15) * 64 + ks * 32 + lhi * 8];
#pragma unroll
            for (int mi = 0; mi < MI; ++mi)
#pragma unroll
                for (int ni = 0; ni < NI; ++ni)
                    acc[mi][ni] = __builtin_amdgcn_mfma_f32_16x16x32_bf16(
                        af[mi], bf[ni], acc[mi][ni], 0, 0, 0);
        }
    }

    float* outf = (float*)outp;
    short* outb = (short*)outp;
#pragma unroll
    for (int mi = 0; mi < MI; ++mi)
#pragma unroll
        for (int ni = 0; ni < NI; ++ni)
#pragma unroll
            for (int r = 0; r < 4; ++r) {
                int row = row0 + wrow0 + mi * 16 + lhi * 4 + r;
                int col = col0 + wcol0 + ni * 16 + l15;
                float v = acc[mi][ni][r];
                if (HAS_BIAS) v += bias[col];
                if (RELU) v = fmaxf(v, 0.f);
                if (RESID) v += resid[(size_t)row * N + col];
                if (OUT_BF16) outb[(size_t)row * N + col] = f2bf(v);
                else outf[(size_t)row * N + col] = v;
            }
}

// ---------------- flash attention (unchanged this round) ----------------
// 1 wave per (b, h, 16 q-rows). qkv bf16 [4096][3072]: q at col h*64, k at
// 1024+h*64, v at 2048+h*64. Online softmax, no scale, non-causal.
__global__ __launch_bounds__(64) void attn_kernel(const short* __restrict__ qkv,
                                                  short* __restrict__ obuf) {
    __shared__ short Pl[16][40];
    const int lane = threadIdx.x;
    const int l15 = lane & 15, lhi = lane >> 4;
    const int bid = blockIdx.x;
    const int b = bid >> 10;          // /(H * T/16)
    const int rem = bid & 1023;
    const int h = rem >> 6;
    const int q0 = (rem & 63) << 4;
    const size_t rbase = (size_t)b * TT;
    const int hq = h * 64;

    short8 aq[2];
#pragma unroll
    for (int ks = 0; ks < 2; ++ks)
        aq[ks] = *(const short8*)&qkv[(rbase + q0 + l15) * NQKV + hq + ks * 32 + lhi * 8];

    float mrun[4], lsum[4];
    f32x4 o[4] = {};
#pragma unroll
    for (int r = 0; r < 4; ++r) { mrun[r] = -INFINITY; lsum[r] = 0.f; }

    for (int st = 0; st < TT; st += 32) {
        f32x4 s[2] = {};
#pragma unroll
        for (int nt = 0; nt < 2; ++nt)
#pragma unroll
            for (int ks = 0; ks < 2; ++ks) {
                short8 kf = *(const short8*)&qkv[(rbase + st + nt * 16 + l15) * NQKV +
                                                 1024 + hq + ks * 32 + lhi * 8];
                s[nt] = __builtin_amdgcn_mfma_f32_16x16x32_bf16(aq[ks], kf, s[nt], 0, 0, 0);
            }
        float fac[4], p[2][4];
#pragma unroll
        for (int r = 0; r < 4; ++r) {
            float tmax = fmaxf(s[0][r], s[1][r]);
#pragma unroll
            for (int off = 1; off < 16; off <<= 1)
                tmax = fmaxf(tmax, __shfl_xor(tmax, off, 16));
            float mnew = fmaxf(mrun[r], tmax);
            fac[r] = __expf(mrun[r] - mnew);
            p[0][r] = __expf(s[0][r] - mnew);
            p[1][r] = __expf(s[1][r] - mnew);
            float rs = p[0][r] + p[1][r];
#pragma unroll
            for (int off = 1; off < 16; off <<= 1) rs += __shfl_xor(rs, off, 16);
            lsum[r] = lsum[r] * fac[r] + rs;
            mrun[r] = mnew;
        }
#pragma unroll
        for (int dt = 0; dt < 4; ++dt)
#pragma unroll
            for (int r = 0; r < 4; ++r) o[dt][r] *= fac[r];

        __syncthreads();
#pragma unroll
        for (int nt = 0; nt < 2; ++nt)
#pragma unroll
            for (int r = 0; r < 4; ++r)
                Pl[lhi * 4 + r][nt * 16 + l15] = f2bf(p[nt][r]);
        __syncthreads();
        short8 pa = *(const short8*)&Pl[l15][lhi * 8];
#pragma unroll
        for (int dt = 0; dt < 4; ++dt) {
            short8 vf;
#pragma unroll
            for (int j = 0; j < 8; ++j)
                vf[j] = qkv[(rbase + st + lhi * 8 + j) * NQKV + 2048 + hq + dt * 16 + l15];
            o[dt] = __builtin_amdgcn_mfma_f32_16x16x32_bf16(pa, vf, o[dt], 0, 0, 0);
        }
    }
#pragma unroll
    for (int r = 0; r < 4; ++r) lsum[r] = 1.0f / lsum[r];
#pragma unroll
    for (int dt = 0; dt < 4; ++dt)
#pragma unroll
        for (int r = 0; r < 4; ++r)
            obuf[(rbase + q0 + lhi * 4 + r) * EE + hq + dt * 16 + l15] =
                f2bf(o[dt][r] * lsum[r]);
}

// ---------------- launch ----------------
extern "C" void kernel_launch(void* const* d_in, const int* in_sizes, int n_in,
                              void* d_out, int out_size, void* d_ws, size_t ws_size,
                              hipStream_t stream) {
    const float* x   = (const float*)d_in[0];
    const float* g1  = (const float*)d_in[1];
    const float* be1 = (const float*)d_in[2];
    const float* Wq  = (const float*)d_in[3];
    const float* Wk  = (const float*)d_in[4];
    const float* Wv  = (const float*)d_in[5];
    const float* Wp  = (const float*)d_in[6];
    const float* bp  = (const float*)d_in[7];
    const float* g2  = (const float*)d_in[8];
    const float* be2 = (const float*)d_in[9];
    const float* W1  = (const float*)d_in[10];
    const float* b1f = (const float*)d_in[11];
    const float* W2  = (const float*)d_in[12];
    const float* b2f = (const float*)d_in[13];

    char* p = (char*)d_ws;
    short* h_bf   = (short*)p; p += (size_t)MM * EE * 2;
    short* wqkv   = (short*)p; p += (size_t)EE * NQKV * 2;   // [3072][1024] W^T
    short* qkv    = (short*)p; p += (size_t)MM * NQKV * 2;
    short* o_bf   = (short*)p; p += (size_t)MM * EE * 2;
    short* wp_bf  = (short*)p; p += (size_t)EE * EE * 2;     // [1024][1024] Wp^T
    float* x1     = (float*)p; p += (size_t)MM * EE * 4;
    short* h2_bf  = (short*)p; p += (size_t)MM * EE * 2;
    short* w1_bf  = (short*)p; p += (size_t)EE * E4 * 2;     // [4096][1024] W1^T
    short* mid_bf = (short*)p; p += (size_t)MM * E4 * 2;
    short* w2_bf  = (short*)p; p += (size_t)E4 * EE * 2;     // [1024][4096] W2^T

    pack_qkv_t<<<dim3(16, 48), 256, 0, stream>>>(Wq, Wk, Wv, wqkv);
    tcvt_kernel<<<dim3(16, 16), 256, 0, stream>>>(Wp, wp_bf, EE, EE);
    tcvt_kernel<<<dim3(64, 16), 256, 0, stream>>>(W1, w1_bf, EE, E4);
    tcvt_kernel<<<dim3(16, 64), 256, 0, stream>>>(W2, w2_bf, E4, EE);

    ln_kernel<<<MM, 256, 0, stream>>>(x, g1, be1, h_bf);

    gemm_bt<128, false, false, false, true>
        <<<dim3(NQKV / 128, MM / 128), 256, 0, stream>>>(h_bf, wqkv, nullptr, nullptr,
                                                         qkv, MM, NQKV, EE);

    attn_kernel<<<BB * HH * (TT / 16), 64, 0, stream>>>(qkv, o_bf);

    gemm_bt<64, true, false, true, false>
        <<<dim3(EE / 64, MM / 128), 256, 0, stream>>>(o_bf, wp_bf, bp, x, x1, MM, EE, EE);

    ln_kernel<<<MM, 256, 0, stream>>>(x1, g2, be2, h2_bf);

    gemm_bt<128, true, true, false, true>
        <<<dim3(E4 / 128, MM / 128), 256, 0, stream>>>(h2_bf, w1_bf, b1f, nullptr,
                                                       mid_bf, MM, E4, EE);

    gemm_bt<64, true, false, true, false>
        <<<dim3(EE / 64, MM / 128), 256, 0, stream>>>(mid_bf, w2_bf, b2f, x1,
                                                      (float*)d_out, MM, EE, E4);
}